// Round 7
// baseline (381.135 us; speedup 1.0000x reference)
//
#include <hip/hip_runtime.h>
#include <hip/hip_bf16.h>
#include <stdint.h>

typedef __hip_bfloat16 bf16;
typedef __attribute__((ext_vector_type(8))) short short8;
typedef __attribute__((ext_vector_type(4))) short short4v;
typedef __attribute__((ext_vector_type(4))) float floatx4;

#define E_DIM 1024
#define S_LEN 2048
#define NB    2
#define NH    16
#define HD    64
#define FFN   4096
#define MTOT  4096   // NB * S_LEN

// 0.125 * log2(e): folded into Q so softmax exp becomes a single v_exp_f32 (2^x)
#define QSCALE 0.18033688011112042f
#define MSCALE -1.4426950408889634e12f

// ---- async global->LDS, 16B per lane (wave-uniform LDS base + lane*16) ----
__device__ __forceinline__ void gl_lds16(const void* g, void* l) {
  __builtin_amdgcn_global_load_lds(
      (__attribute__((address_space(1))) void*)(g),
      (__attribute__((address_space(3))) void*)(l), 16, 0, 0);
}

#define VMW(N)  do { asm volatile("s_waitcnt vmcnt(" #N ")" ::: "memory"); \
                     __builtin_amdgcn_sched_barrier(0); } while (0)
#define LGKM0   do { asm volatile("s_waitcnt lgkmcnt(0)" ::: "memory"); } while (0)
#define BARR    do { asm volatile("s_barrier" ::: "memory"); } while (0)

// raw v_exp_f32: D = 2^S0 (non-volatile: pure, schedulable/CSE-able)
__device__ __forceinline__ float exp2_fast(float x) {
  float r;
  asm("v_exp_f32 %0, %1" : "=v"(r) : "v"(x));
  return r;
}

// LDS chunk swizzles for flash_attn (chunk = 16B = 8 bf16; 8 chunks/64-elem row)
__device__ __forceinline__ int fswz_v(int row) { return row & 7; }
__device__ __forceinline__ int fswz_k(int row) {
  return ((row ^ (row >> 3)) & 3) | ((((row >> 3) ^ (row >> 4)) & 1) << 2);
}

__device__ __forceinline__ float bf16bits2float(short s) {
  union { unsigned u; float f; } c;
  c.u = ((unsigned)(unsigned short)s) << 16;
  return c.f;
}

// ---------------------------------------------------------------------------
// fp32 -> bf16 convert (4 elems/thread)
// ---------------------------------------------------------------------------
__global__ __launch_bounds__(256)
void cvt_bf16(const float* __restrict__ in, bf16* __restrict__ out) {
  const size_t i = ((size_t)blockIdx.x * 256 + threadIdx.x) * 4;
  float4 v = *(const float4*)(in + i);
  out[i + 0] = __float2bfloat16(v.x);
  out[i + 1] = __float2bfloat16(v.y);
  out[i + 2] = __float2bfloat16(v.z);
  out[i + 3] = __float2bfloat16(v.w);
}

// ---------------------------------------------------------------------------
// All weight transposes in one kernel: 12 z-slices of 1024x1024 blocks.
// ---------------------------------------------------------------------------
__global__ __launch_bounds__(256)
void transpose_all(const float* __restrict__ wq, const float* __restrict__ wk,
                   const float* __restrict__ wv, const float* __restrict__ wo,
                   const float* __restrict__ f1, const float* __restrict__ f2,
                   bf16* __restrict__ W3T, bf16* __restrict__ woT,
                   bf16* __restrict__ f1T, bf16* __restrict__ f2T) {
  const int z = blockIdx.z;
  const float* in;
  bf16* out;
  int inStride, outStride, rOff, cOff;
  if (z < 4) {
    in = (z == 0) ? wq : (z == 1) ? wk : (z == 2) ? wv : wo;
    out = (z < 3) ? (W3T + (size_t)z * 1024 * 1024) : woT;
    inStride = 1024; outStride = 1024; rOff = 0; cOff = 0;
  } else if (z < 8) {
    in = f1; out = f1T; inStride = 4096; outStride = 1024;
    rOff = 0; cOff = (z - 4) * 1024;
  } else {
    in = f2; out = f2T; inStride = 1024; outStride = 4096;
    rOff = (z - 8) * 1024; cOff = 0;
  }
  __shared__ float tile[32][33];
  const int tx = threadIdx.x & 31;
  const int ty = threadIdx.x >> 5;
  const int c0 = blockIdx.x * 32;
  const int r0 = blockIdx.y * 32;
#pragma unroll
  for (int j = 0; j < 32; j += 8)
    tile[ty + j][tx] =
        in[(size_t)(rOff + r0 + ty + j) * inStride + cOff + c0 + tx];
  __syncthreads();
#pragma unroll
  for (int j = 0; j < 32; j += 8)
    out[(size_t)(cOff + c0 + ty + j) * outStride + rOff + r0 + tx] =
        __float2bfloat16(tile[tx][ty + j]);
}

// concat biases (Q bias pre-scaled by 0.125*log2e for exp2 softmax)
__global__ __launch_bounds__(256)
void prep_bias(const float* __restrict__ qb, const float* __restrict__ kb,
               const float* __restrict__ vb, float* __restrict__ out) {
  const int i = blockIdx.x * 256 + threadIdx.x;
  float v = (i < 1024) ? qb[i] * QSCALE
                       : ((i < 2048) ? kb[i - 1024] : vb[i - 2048]);
  out[i] = v;
}

// ---------------------------------------------------------------------------
// GEMM: C(M,N) = A(M,K) @ B^T, B stored (N,K) row-major, both bf16.
// 128x128 tile, BK=32, 4 waves (2M x 2N), per-wave 64x64 output (m97-class
// geometry -> 32 KiB LDS, ~165 regs, 3 blocks/CU: multi-block TLP absorbs
// barrier/vmcnt stalls and makes duration insensitive to block placement).
// Deep counted-vmcnt pipeline, 2 barriers per K-step:
//  step s entry: VMW(4) [tile s+1's 4 loads in flight; tile s landed]; BARR
//  region 1: 8 ds_read_b128 (aF,bF) + 8 MFMA (ni 0-1); LGKM0; BARR
//  region 2: stage tile s+2 (4 loads -> buf p) under 8 pure-register MFMA.
// LDS tiles [128][32] bf16; XOR-swizzle (16B granule ^ (row&3)) applied on
// per-lane GLOBAL source (gload_lds dest linear) and on ds_read addrs.
// Modes: 0 fp32 partial (z<2 -> Cout, z>=2 -> Cout2), 1 bias+ReLU bf16,
//        2 fused QKV scatter (Q scaled by QSCALE). Requires M%128==0,
//        N%128==0, Kpart%32==0, Kpart>=64 (NS>=2), (gridX*gridY)%8==0.
// ---------------------------------------------------------------------------
__global__ __launch_bounds__(256, 3)
void gemm128(const bf16* __restrict__ A, const bf16* __restrict__ B,
             const float* __restrict__ bias, void* __restrict__ Cout,
             void* __restrict__ Cout2,
             int M, int N, int Kpart, int lda, int mode) {
  __shared__ alignas(16) bf16 sA[2][128 * 32];
  __shared__ alignas(16) bf16 sB[2][128 * 32];
  const int tid   = threadIdx.x;
  const int wave  = tid >> 6;         // 0..3
  const int lane  = tid & 63;
  const int row16 = lane & 15;
  const int quad  = lane >> 4;        // 0..3 (granule within 32-col row)
  const int sw3   = row16 & 3;

  // XCD-aware bijective swizzle of the (x,y) plane (nwg % 8 == 0 for all calls)
  const int gx = gridDim.x;
  const int nwg = gx * gridDim.y;
  const int cpx = nwg >> 3;
  int id = blockIdx.y * gx + blockIdx.x;
  id = (id & 7) * cpx + (id >> 3);
  const int m0 = (id % gx) * 128;
  const int n0 = (id / gx) * 128;

  const int wm = (wave >> 1) * 64;    // wave row offset in tile
  const int wn = (wave & 1) * 64;     // wave col offset in tile
  const int koff = blockIdx.z * Kpart;
  const int NS = Kpart >> 5;          // 32-K tiles (>=2)

  floatx4 acc[4][4];
#pragma unroll
  for (int i = 0; i < 4; i++)
#pragma unroll
    for (int j = 0; j < 4; j++) {
      floatx4 z = {0.f, 0.f, 0.f, 0.f};
      acc[i][j] = z;
    }

  // stage one K-tile (128 rows x 32 K of A and B) into buf p: 4 gl_lds16/thr.
  // LDS dest linear (row = 64j + wave*16 + lane>>2, granule = lane&3);
  // global source pre-swizzled: granule g = (lane&3) ^ (row&3).
  auto stage_tile = [&](int t, int p) {
    const int k0 = koff + t * 32;
#pragma unroll
    for (int j = 0; j < 2; ++j) {
      const int r = j * 64 + wave * 16 + (lane >> 2);
      const int g = (lane & 3) ^ (r & 3);
      gl_lds16(A + (size_t)(m0 + r) * lda + k0 + g * 8,
               sA[p] + (j * 64 + wave * 16) * 32);
      gl_lds16(B + (size_t)(n0 + r) * lda + k0 + g * 8,
               sB[p] + (j * 64 + wave * 16) * 32);
    }
  };

  short8 aF[4], bF[4];
  auto read_frags = [&](int p) {
#pragma unroll
    for (int i = 0; i < 4; ++i) {
      const int ra = wm + i * 16 + row16;
      const int rb = wn + i * 16 + row16;
      aF[i] = *(const short8*)(sA[p] + ra * 32 + ((quad ^ sw3) << 3));
      bF[i] = *(const short8*)(sB[p] + rb * 32 + ((quad ^ sw3) << 3));
    }
  };
  auto qmf = [&](int ni0) {
    __builtin_amdgcn_s_setprio(1);
#pragma unroll
    for (int mi = 0; mi < 4; ++mi)
#pragma unroll
      for (int ni = 0; ni < 2; ++ni)
        acc[mi][ni0 + ni] = __builtin_amdgcn_mfma_f32_16x16x32_bf16(
            aF[mi], bF[ni0 + ni], acc[mi][ni0 + ni], 0, 0, 0);
    __builtin_amdgcn_s_setprio(0);
  };

  // prologue: tiles 0 and 1 staged (8 loads/thread)
  stage_tile(0, 0);
  stage_tile(1, 1);

  for (int s = 0; s < NS; ++s) {
    const int p = s & 1;
    // entry: tile s+1's 4 loads may remain in flight; tile s landed
    if (s + 1 < NS) VMW(4); else VMW(0);
    BARR;
    // region 1: all buf-p reads + half the MFMAs (compiler interleaves)
    read_frags(p);
    qmf(0);
    LGKM0;        // this wave's ds_reads drained (stage below overwrites buf p)
    BARR;         // all waves' buf-p reads done -> buf p reusable
    // region 2: stage tile s+2 under pure-register MFMA
    if (s + 2 < NS) stage_tile(s + 2, p);
    qmf(2);
  }

  float bval[4] = {0.f, 0.f, 0.f, 0.f};
  if (mode != 0) {
#pragma unroll
    for (int ni = 0; ni < 4; ni++) bval[ni] = bias[n0 + wn + ni * 16 + row16];
  }

#pragma unroll
  for (int mi = 0; mi < 4; mi++) {
#pragma unroll
    for (int ni = 0; ni < 4; ni++) {
      const int col = n0 + wn + ni * 16 + row16;
      if (mode == 0) {
        float* co = (float*)((blockIdx.z < 2) ? Cout : Cout2) +
                    (size_t)(blockIdx.z & 1) * M * N;
#pragma unroll
        for (int r = 0; r < 4; r++) {
          const int row = m0 + wm + mi * 16 + quad * 4 + r;
          co[(size_t)row * N + col] = acc[mi][ni][r];
        }
      } else if (mode == 1) {
#pragma unroll
        for (int r = 0; r < 4; r++) {
          const int row = m0 + wm + mi * 16 + quad * 4 + r;
          float v = acc[mi][ni][r] + bval[ni];
          v = v > 0.f ? v : 0.f;
          ((bf16*)Cout)[(size_t)row * N + col] = __float2bfloat16(v);
        }
      } else {
        // fused QKV scatter
        const int mat = col >> 10;
        const int c10 = col & 1023;
        const int hh = c10 >> 6, dd = c10 & 63;
        const float scl = (mat == 0) ? QSCALE : 1.0f;
        bf16* qout = (bf16*)Cout;
        const int rbase = m0 + wm + mi * 16 + quad * 4;
        const int b2 = rbase >> 11, ss = rbase & 2047;
        const size_t bh = (size_t)b2 * NH + hh;
        if (mat == 2) {
          bf16* vt = qout + (1 << 23);
          short4v pv;
#pragma unroll
          for (int r = 0; r < 4; r++) {
            bf16 t = __float2bfloat16(acc[mi][ni][r] + bval[ni]);
            pv[r] = *(short*)&t;
          }
          *(short4v*)(vt + (bh * HD + dd) * S_LEN + ss) = pv;
        } else {
          bf16* o = (mat == 1) ? (qout + (1 << 22)) : qout;
#pragma unroll
          for (int r = 0; r < 4; r++) {
            float v = acc[mi][ni][r] * scl + bval[ni];
            o[(bh * S_LEN + ss + r) * HD + dd] = __float2bfloat16(v);
          }
        }
      }
    }
  }
}

// ---------------------------------------------------------------------------
// Flash attention: one block per (128-q tile, bh); 4 waves x 32 q-rows each.
// Per wave, two 16-row q groups (A at qg, B at qg+16) share every K/V LDS
// fragment read and all staging: 36 MFMA per tile vs 16 ds_read_b128.
// Fixed-max streaming softmax with exp2 (Q pre-scaled 0.125*log2e, mask
// pre-scaled -1e12*log2e). Denominator via all-ones MFMA (lacc[0]).
// K/V double-buffered, counted vmcnt. LDS 40KB; grid 512 -> 2 blocks/CU.
// ---------------------------------------------------------------------------
__global__ __launch_bounds__(256, 2)
void flash_attn(const bf16* __restrict__ Q, const bf16* __restrict__ K,
                const bf16* __restrict__ Vt, const float* __restrict__ mask,
                bf16* __restrict__ Out) {
  __shared__ alignas(16) bf16 sK[2][64 * 64];  // [key][d], chunk-swz fswz_k
  __shared__ alignas(16) bf16 sV[2][64 * 64];  // [d][key], chunk-swz fswz_v
  __shared__ alignas(16) float sM[S_LEN];      // MSCALE * mask[b][*]

  const int tid   = threadIdx.x;
  const int wave  = tid >> 6;
  const int lane  = tid & 63;
  const int row16 = lane & 15;
  const int quad  = lane >> 4;
  const int bh = blockIdx.y;
  const int b = bh >> 4, h = bh & 15;
  const int q0 = blockIdx.x * 128;
  const int qg = q0 + wave * 32 + row16;       // group A; group B = qg + 16

  const bf16* qpA = Q + ((size_t)bh * S_LEN + qg) * HD;
  const bf16* qpB = qpA + 16 * HD;
  short8 qa0 = *(const short8*)(qpA + quad * 8);
  short8 qa1 = *(const short8*)(qpA + 32 + quad * 8);
  short8 qb0 = *(const short8*)(qpB + quad * 8);
  short8 qb1 = *(const short8*)(qpB + 32 + quad * 8);

  for (int i = tid; i < S_LEN / 4; i += 256) {
    float4 mv = ((const float4*)(mask + (size_t)b * S_LEN))[i];
    float4 w = {MSCALE * mv.x, MSCALE * mv.y, MSCALE * mv.z, MSCALE * mv.w};
    ((float4*)sM)[i] = w;
  }
  LGKM0;   // sM ds_writes drained before the first barrier publishes them

  short8 ones;
#pragma unroll
  for (int j = 0; j < 8; j++) ones[j] = (short)0x3F80;  // bf16 1.0

  floatx4 laccA = {0.f, 0.f, 0.f, 0.f};
  floatx4 laccB = {0.f, 0.f, 0.f, 0.f};
  floatx4 ovA[4], ovB[4];
#pragma unroll
  for (int i = 0; i < 4; i++) {
    floatx4 z = {0.f,0.f,0.f,0.f};
    ovA[i] = z; ovB[i] = z;
  }

  const bf16* Kbase = K + (size_t)bh * S_LEN * HD;
  const bf16* Vbase = Vt + (size_t)bh * HD * S_LEN;
  const int NT = S_LEN / 64;

  auto stage = [&](int kt) {
    const bf16* Kg = Kbase + (size_t)kt * 64 * HD;
    const bf16* Vg = Vbase + kt * 64;
    bf16* dK = sK[kt & 1];
    bf16* dV = sV[kt & 1];
#pragma unroll
    for (int j = 0; j < 2; ++j) {
      const int ch = wave * 2 + j;
      const int row = ch * 8 + (lane >> 3);
      const int sc_ = lane & 7;
      gl_lds16(Kg + row * 64 + ((sc_ ^ fswz_k(row)) * 8), dK + ch * 512);
      gl_lds16(Vg + (size_t)row * S_LEN + ((sc_ ^ fswz_v(row)) * 8), dV + ch * 512);
    }
  };

  stage(0);

  for (int kt = 0; kt < NT; ++kt) {
    if (kt + 1 < NT) {
      stage(kt + 1);   // 4 loads into buf^1 (readers finished at prev BARR)
      VMW(4);          // kt's 4 loads landed; kt+1's stay in flight
    } else {
      VMW(0);
    }
    BARR;              // all waves have kt's K/V (and, at kt=0, sM)

    const bf16* Kb = sK[kt & 1];
    const bf16* Vb = sV[kt & 1];

    floatx4 scA[4], scB[4];
#pragma unroll
    for (int mi = 0; mi < 4; mi++) {
      const int row = ((row16 >> 2) << 3) + (row16 & 3) + ((mi & 1) << 2) + ((mi >> 1) << 5);
      const int fk = fswz_k(row);
      short8 kf0 = *(const short8*)(Kb + row * 64 + ((quad ^ fk) << 3));
      short8 kf1 = *(const short8*)(Kb + row * 64 + (((4 + quad) ^ fk) << 3));
      floatx4 zA = {0.f, 0.f, 0.f, 0.f};
      zA = __builtin_amdgcn_mfma_f32_16x16x32_bf16(kf0, qa0, zA, 0, 0, 0);
      scA[mi] = __builtin_amdgcn_mfma_f32_16x16x32_bf16(kf1, qa1, zA, 0, 0, 0);
      floatx4 zB = {0.f, 0.f, 0.f, 0.f};
      zB = __builtin_amdgcn_mfma_f32_16x16x32_bf16(kf0, qb0, zB, 0, 0, 0);
      scB[mi] = __builtin_amdgcn_mfma_f32_16x16x32_bf16(kf1, qb1, zB, 0, 0, 0);
    }

    // p = 2^(sc + maskbias)  (logits already scaled by log2e)
#pragma unroll
    for (int mi = 0; mi < 4; mi++) {
      float4 mv = *(const float4*)(sM + kt * 64 + (quad << 3) + ((mi & 1) << 2) + ((mi >> 1) << 5));
      scA[mi][0] = exp2_fast(scA[mi][0] + mv.x);
      scA[mi][1] = exp2_fast(scA[mi][1] + mv.y);
      scA[mi][2] = exp2_fast(scA[mi][2] + mv.z);
      scA[mi][3] = exp2_fast(scA[mi][3] + mv.w);
      scB[mi][0] = exp2_fast(scB[mi][0] + mv.x);
      scB[mi][1] = exp2_fast(scB[mi][1] + mv.y);
      scB[mi][2] = exp2_fast(scB[mi][2] + mv.z);
      scB[mi][3] = exp2_fast(scB[mi][3] + mv.w);
    }

    short8 pfA[2], pfB[2];
#pragma unroll
    for (int ks = 0; ks < 2; ks++)
#pragma unroll
      for (int jp = 0; jp < 4; jp++) {
        const int mi = 2 * ks + (jp >> 1);
        const int r0 = (jp & 1) * 2;
        bf16 a0 = __float2bfloat16(scA[mi][r0]);
        bf16 a1 = __float2bfloat16(scA[mi][r0 + 1]);
        pfA[ks][2 * jp]     = *(short*)&a0;
        pfA[ks][2 * jp + 1] = *(short*)&a1;
        bf16 b0 = __float2bfloat16(scB[mi][r0]);
        bf16 b1 = __float2bfloat16(scB[mi][r0 + 1]);
        pfB[ks][2 * jp]     = *(short*)&b0;
        pfB[ks][2 * jp + 1] = *(short*)&b1;
      }

    // denominator partial sums on the MFMA pipe (frees VALU)
    laccA = __builtin_amdgcn_mfma_f32_16x16x32_bf16(ones, pfA[0], laccA, 0, 0, 0);
    laccA = __builtin_amdgcn_mfma_f32_16x16x32_bf16(ones, pfA[1], laccA, 0, 0, 0);
    laccB = __builtin_amdgcn_mfma_f32_16x16x32_bf16(ones, pfB[0], laccB, 0, 0, 0);
    laccB = __builtin_amdgcn_mfma_f32_16x16x32_bf16(ones, pfB[1], laccB, 0, 0, 0);

#pragma unroll
    for (int mi = 0; mi < 4; mi++) {
      const int row = mi * 16 + row16;
      const int fv = fswz_v(row);
      short8 v0 = *(const short8*)(Vb + row * 64 + ((quad ^ fv) << 3));
      short8 v1 = *(const short8*)(Vb + row * 64 + (((4 + quad) ^ fv) << 3));
      ovA[mi] = __builtin_amdgcn_mfma_f32_16x16x32_bf16(v0, pfA[0], ovA[mi], 0, 0, 0);
      ovA[mi] = __builtin_amdgcn_mfma_f32_16x16x32_bf16(v1, pfA[1], ovA[mi], 0, 0, 0);
      ovB[mi] = __builtin_amdgcn_mfma_f32_16x16x32_bf16(v0, pfB[0], ovB[mi], 0, 0, 0);
      ovB[mi] = __builtin_amdgcn_mfma_f32_16x16x32_bf16(v1, pfB[1], ovB[mi], 0, 0, 0);
    }
    BARR;   // readers done -> next iter may overwrite buf^1
  }

  const float invA = 1.0f / laccA[0];
  const float invB = 1.0f / laccB[0];
#pragma unroll
  for (int mi = 0; mi < 4; mi++) {
    short4v pva, pvb;
#pragma unroll
    for (int r = 0; r < 4; r++) {
      bf16 ta = __float2bfloat16(ovA[mi][r] * invA);
      pva[r] = *(short*)&ta;
      bf16 tb = __float2bfloat16(ovB[mi][r] * invB);
      pvb[r] = *(short*)&tb;
    }
    *(short4v*)(Out + ((size_t)(b * S_LEN + qg)) * E_DIM + h * HD + mi * 16 + quad * 4) = pva;
    *(short4v*)(Out + ((size_t)(b * S_LEN + qg + 16)) * E_DIM + h * HD + mi * 16 + quad * 4) = pvb;
  }
}

// ---------------------------------------------------------------------------
// Split-K reduce (2 or 4 partials) + residual + bias + LayerNorm, 1 block/row.
// ---------------------------------------------------------------------------
__global__ __launch_bounds__(256)
void ln_reduce(const float* __restrict__ p0, const float* __restrict__ p1,
               const float* __restrict__ p2, const float* __restrict__ p3,
               const float* __restrict__ resf, const bf16* __restrict__ resb,
               const float* __restrict__ bias, const float* __restrict__ g,
               const float* __restrict__ be, float* __restrict__ outf,
               bf16* __restrict__ outb) {
  const int row = blockIdx.x;
  const int tid = threadIdx.x;
  const size_t base = (size_t)row * 1024;
  const int c = tid * 4;
  float4 a = *(const float4*)(p0 + base + c);
  float4 bq = *(const float4*)(p1 + base + c);
  float4 xv;
  xv.x = a.x + bq.x;
  xv.y = a.y + bq.y;
  xv.z = a.z + bq.z;
  xv.w = a.w + bq.w;
  if (p2) {
    float4 a2 = *(const float4*)(p2 + base + c);
    float4 a3 = *(const float4*)(p3 + base + c);
    xv.x += a2.x + a3.x;
    xv.y += a2.y + a3.y;
    xv.z += a2.z + a3.z;
    xv.w += a2.w + a3.w;
  }
  float4 rv;
  if (resf) {
    rv = *(const float4*)(resf + base + c);
  } else {
    short4v rb = *(const short4v*)((const short*)resb + base + c);
    rv.x = bf16bits2float(rb[0]);
    rv.y = bf16bits2float(rb[1]);
    rv.z = bf16bits2float(rb[2]);
    rv.w = bf16bits2float(rb[3]);
  }
  float4 bi = *(const float4*)(bias + c);
  xv.x += rv.x + bi.x;
  xv.y += rv.y + bi.y;
  xv.z += rv.z + bi.z;
  xv.w += rv.w + bi.w;
  float s  = xv.x + xv.y + xv.z + xv.w;
  float s2 = xv.x * xv.x + xv.y * xv.y + xv.z * xv.z + xv.w * xv.w;
#pragma unroll
  for (int d = 1; d < 64; d <<= 1) {
    s  += __shfl_xor(s, d);
    s2 += __shfl_xor(s2, d);
  }
  __shared__ float red[2][4];
  const int wave = tid >> 6;
  if ((tid & 63) == 0) { red[0][wave] = s; red[1][wave] = s2; }
  __syncthreads();
  s  = red[0][0] + red[0][1] + red[0][2] + red[0][3];
  s2 = red[1][0] + red[1][1] + red[1][2] + red[1][3];
  const float mu  = s * (1.0f / 1024.0f);
  const float var = s2 * (1.0f / 1024.0f) - mu * mu;
  const float rs  = rsqrtf(var + 1e-9f);
  float4 gg = *(const float4*)(g + c);
  float4 bb = *(const float4*)(be + c);
  float4 y;
  y.x = (xv.x - mu) * rs * gg.x + bb.x;
  y.y = (xv.y - mu) * rs * gg.y + bb.y;
  y.z = (xv.z - mu) * rs * gg.z + bb.z;
  y.w = (xv.w - mu) * rs * gg.w + bb.w;
  if (outf) *(float4*)(outf + base + c) = y;
  if (outb) {
    bf16* o = outb + base + c;
    o[0] = __float2bfloat16(y.x);
    o[1] = __float2bfloat16(y.y);
    o[2] = __float2bfloat16(y.z);
    o[3] = __float2bfloat16(y.w);
  }
}

// ---------------------------------------------------------------------------
extern "C" void kernel_launch(void* const* d_in, const int* in_sizes, int n_in,
                              void* d_out, int out_size, void* d_ws,
                              size_t ws_size, hipStream_t stream) {
  const float* x    = (const float*)d_in[0];
  const float* mask = (const float*)d_in[1];
  const float* wq_w = (const float*)d_in[2];
  const float* wq_b = (const float*)d_in[3];
  const float* wk_w = (const float*)d_in[4];
  const float* wk_b = (const float*)d_in[5];
  const float* wv_w = (const float*)d_in[6];
  const float* wv_b = (const float*)d_in[7];
  const float* wo_w = (const float*)d_in[8];
  const float* wo_b = (const float*)d_in[9];
  const float* f1_w = (const float*)d_in[10];
  const float* f1_b = (const float*)d_in[11];
  const float* f2_w = (const float*)d_in[12];
  const float* f2_b = (const float*)d_in[13];
  const float* ln1_g = (const float*)d_in[14];
  const float* ln1_b = (const float*)d_in[15];
  const float* ln2_g = (const float*)d_in[16];
  const float* ln2_b = (const float*)d_in[17];
  float* out = (float*)d_out;

  char* ws = (char*)d_ws;
  const size_t MB = 1u << 20;
  bf16*  xbf   = (bf16*)(ws + 0 * MB);
  bf16*  W3T   = (bf16*)(ws + 8 * MB);
  bf16*  woT   = (bf16*)(ws + 14 * MB);
  float* bqkv  = (float*)(ws + 16 * MB);
  bf16*  Qb    = (bf16*)(ws + 17 * MB);
  bf16*  attnb = (bf16*)(ws + 0 * MB);
  bf16*  ffn1  = (bf16*)(ws + 17 * MB);
  bf16*  f1T   = (bf16*)(ws + 49 * MB);
  bf16*  f2T   = (bf16*)(ws + 57 * MB);
  float* P01   = (float*)(ws + 65 * MB);
  bf16*  hbf   = (bf16*)(ws + 97 * MB);
  float* P23   = (float*)(ws + 105 * MB);
  const size_t PS = (size_t)MTOT * E_DIM;   // elems per partial

  // split-K factor for the N=1024 GEMMs: 4 if workspace fits 4 partials
  const int KS = (ws_size >= (size_t)137 * MB) ? 4 : 2;
  const float* p2 = (KS == 4) ? P23 : nullptr;
  const float* p3 = (KS == 4) ? P23 + PS : nullptr;

  // pre-pass
  cvt_bf16<<<4096, 256, 0, stream>>>(x, xbf);
  transpose_all<<<dim3(32, 32, 12), 256, 0, stream>>>(
      wq_w, wk_w, wv_w, wo_w, f1_w, f2_w, W3T, woT, f1T, f2T);
  prep_bias<<<12, 256, 0, stream>>>(wq_b, wk_b, wv_b, bqkv);

  // fused QKV projection -> Qb (B*H,S,D), Kb, Vt (B*H,D,S)
  gemm128<<<dim3(32, 24, 1), 256, 0, stream>>>(
      xbf, W3T, bqkv, Qb, nullptr, MTOT, 3 * E_DIM, E_DIM, E_DIM, 2);

  // attention: 128 q-rows per block (4 waves x 32)
  flash_attn<<<dim3(S_LEN / 128, NB * NH), 256, 0, stream>>>(
      Qb, Qb + (1 << 22), Qb + (1 << 23), mask, attnb);

  // output projection, split-K -> fp32 partials
  gemm128<<<dim3(32, 8, KS), 256, 0, stream>>>(
      attnb, woT, nullptr, P01, P23, MTOT, E_DIM, E_DIM / KS, E_DIM, 0);

  // h = LN(sum(partials)+wo_b + x) -> bf16 only
  ln_reduce<<<MTOT, 256, 0, stream>>>(P01, P01 + PS, p2, p3, x, nullptr,
                                      wo_b, ln1_g, ln1_b, nullptr, hbf);

  // FFN1: relu(h @ f1 + b) -> bf16
  gemm128<<<dim3(32, 32, 1), 256, 0, stream>>>(
      hbf, f1T, f1_b, ffn1, nullptr, MTOT, FFN, E_DIM, E_DIM, 1);

  // FFN2, split-K -> fp32 partials
  gemm128<<<dim3(32, 8, KS), 256, 0, stream>>>(
      ffn1, f2T, nullptr, P01, P23, MTOT, E_DIM, FFN / KS, FFN, 0);

  // out = LN(sum(partials)+f2_b + h)
  ln_reduce<<<MTOT, 256, 0, stream>>>(P01, P01 + PS, p2, p3, nullptr, hbf,
                                      f2_b, ln2_g, ln2_b, out, nullptr);
}